// Round 6
// baseline (247.321 us; speedup 1.0000x reference)
//
#include <hip/hip_runtime.h>
#include <math.h>

// Single-query MHA, algebraically collapsed:
//   s[l,h] = x_l . p_h         (p_h = Wk_h^T q_h / sqrt(D); k-bias shift cancels in softmax)
//   z_h    = sum_l softmax(s)_lh * x_l
//   attn   = Wv z + bv ; out = Wo attn + bo
// All fp32. No max-subtraction needed: |s| ~ N(0,1), max ~ 5 << 88 (fp32 exp range).
//
// v6 (attn_fused5): P lives in REGISTERS (wave w holds 4 heads x 16 floats/lane
// = 64 VGPRs), so the score phase reads each x-row slice from LDS once for 4
// heads (8 ds_read_b128/row vs 32 when P was in LDS -- fused2/3/4 were all
// LDS-pipe-bound at ~670 cyc/row vs HBM 400). x staged by global_load_lds
// (zero staging VGPRs), double-buffered 8-row tiles (64KB -> 2 blocks/CU).
// Phase-B weights broadcast via one ds_read_b32 + v_readlane (VALU, not LDS).

#define L_SEQ   32768
#define E_DIM   1024
#define NHEAD   8
#define HDIM    128
#define TILE_R  8
#define WAVES_M 8            // 512 threads

// ---------------- q = Wq x0 + bq : wave-per-output GEMV ----------------
__global__ __launch_bounds__(256) void proj_q(
    const float* __restrict__ W, const float* __restrict__ bias,
    const float* __restrict__ x, float* __restrict__ q)
{
  const int t = threadIdx.x, wave = t >> 6, lane = t & 63;
  const int o = blockIdx.x * 4 + wave;
  const float4* Wr = (const float4*)(W + (size_t)o * E_DIM);
  const float4* xr = (const float4*)x;   // row 0 of x
  float a = 0.f;
#pragma unroll
  for (int k = 0; k < 4; ++k) {
    float4 wv = Wr[lane + 64 * k];
    float4 xv = xr[lane + 64 * k];
    a += wv.x * xv.x + wv.y * xv.y + wv.z * xv.z + wv.w * xv.w;
  }
#pragma unroll
  for (int m = 1; m < 64; m <<= 1) a += __shfl_xor(a, m, 64);
  if (lane == 0) q[o] = a + bias[o];
}

// ---------------- P_T[h][e] = (1/sqrt(D)) sum_d q[h*128+d] * Wk[h*128+d][e] ----------------
__global__ __launch_bounds__(128) void make_p(
    const float* __restrict__ W, const float* __restrict__ q,
    float* __restrict__ P_T)
{
  const int h = blockIdx.y;
  const int e = blockIdx.x * 128 + threadIdx.x;
  const float* qh = q + h * HDIM;                              // lane-uniform (scalarized)
  const float* Wb = W + ((size_t)E_DIM + (size_t)h * HDIM) * E_DIM + e;  // Wk block rows
  float a0 = 0.f, a1 = 0.f, a2 = 0.f, a3 = 0.f;
#pragma unroll 4
  for (int d = 0; d < HDIM; d += 4) {
    a0 += qh[d + 0] * Wb[(size_t)(d + 0) * E_DIM];
    a1 += qh[d + 1] * Wb[(size_t)(d + 1) * E_DIM];
    a2 += qh[d + 2] * Wb[(size_t)(d + 2) * E_DIM];
    a3 += qh[d + 3] * Wb[(size_t)(d + 3) * E_DIM];
  }
  P_T[h * E_DIM + e] = ((a0 + a1) + (a2 + a3)) * 0.08838834764831845f;   // 1/sqrt(128)
}

// ---------------- fused single-pass attention core ----------------
// Per 8-row tile (double-buffered):
//   stage: wave w DMAs row w of tile t+1 into buf^1 (global_load_lds, 16B/lane)
//   score: wave w = (rg, hg): rows {2rg, 2rg+1} x heads {4hg..4hg+3} from
//          x_tile[buf] (LDS) x P (regs); 10-shfl transpose-reduce; lanes<8
//          write w_tile[row][head]; 1 exp/lane.
//   phase B: thread t owns cols {2t,2t+1} x 8 heads (16 acc VGPRs); w values
//          via one ds_read_b32 + v_readlane broadcasts.
__global__ __launch_bounds__(512, 2) void attn_fused5(
    const float* __restrict__ x,
    const float* __restrict__ P_T,       // [8][1024]
    float* __restrict__ partial_z,       // [nblk][8][1024]
    float* __restrict__ partial_sumw,    // [nblk][8]
    int rows_per_blk)
{
  __shared__ __align__(16) float x_tile[2][TILE_R][E_DIM];   // 64 KB
  __shared__ __align__(16) float w_tile[TILE_R][NHEAD];      // 256 B
  __shared__ __align__(16) float sw_stage[WAVES_M][4];       // 128 B

  const int t = threadIdx.x;
  const int wave = t >> 6;
  const int lane = t & 63;
  const size_t row0 = (size_t)blockIdx.x * rows_per_blk;
  const int ntiles = rows_per_blk / TILE_R;
  const int rg = wave >> 1;          // row group: rows {2rg, 2rg+1}
  const int hg = wave & 1;           // head group: heads {4hg..4hg+3}

  // transpose-reduce mapping for v[8], i = r_l*4 + h_l:
  // after 3 splitting levels lane holds j = b0*4 + b1*2 + b2 (bk = bit k of lane)
  const int r_l = lane & 1;
  const int h_l = (((lane >> 1) & 1) << 1) | ((lane >> 2) & 1);

  // P slices in registers: p[j][k] = head (4hg+j), float4 index (lane + 64k)
  float4 p[4][4];
#pragma unroll
  for (int j = 0; j < 4; ++j) {
    const float4* pr = (const float4*)(P_T + (size_t)(4 * hg + j) * E_DIM);
#pragma unroll
    for (int k = 0; k < 4; ++k) p[j][k] = pr[lane + 64 * k];
  }

  float acc[16];
#pragma unroll
  for (int i = 0; i < 16; ++i) acc[i] = 0.f;
  float sumw_own = 0.f;

  // stage tile 0 -> buf 0 (wave w stages row w; LDS dst = uniform base + lane*16)
  {
    const float* g = x + (row0 + wave) * E_DIM;
#pragma unroll
    for (int k = 0; k < 4; ++k)
      __builtin_amdgcn_global_load_lds(
          (const __attribute__((address_space(1))) void*)(g + k * 256 + lane * 4),
          (__attribute__((address_space(3))) void*)(&x_tile[0][wave][k * 256]),
          16, 0, 0);
  }

  for (int tile = 0; tile < ntiles; ++tile) {
    const int buf = tile & 1;
    __syncthreads();   // buf staged (drains own DMA) + prior readers of buf^1 done

    // issue DMA for next tile into the other buffer (overlaps score+phaseB)
    if (tile + 1 < ntiles) {
      const float* g = x + (row0 + (size_t)(tile + 1) * TILE_R + wave) * E_DIM;
#pragma unroll
      for (int k = 0; k < 4; ++k)
        __builtin_amdgcn_global_load_lds(
            (const __attribute__((address_space(1))) void*)(g + k * 256 + lane * 4),
            (__attribute__((address_space(3))) void*)(&x_tile[buf ^ 1][wave][k * 256]),
            16, 0, 0);
    }

    // ---- score: 2 rows x 4 heads per wave, P from regs, x from LDS
    float v[8];
#pragma unroll
    for (int i = 0; i < 8; ++i) v[i] = 0.f;
#pragma unroll
    for (int r = 0; r < 2; ++r) {
      const float4* xr = (const float4*)&x_tile[buf][2 * rg + r][0];
#pragma unroll
      for (int k = 0; k < 4; ++k) {
        const float4 xv = xr[lane + 64 * k];
#pragma unroll
        for (int j = 0; j < 4; ++j)
          v[r * 4 + j] += xv.x * p[j][k].x + xv.y * p[j][k].y +
                          xv.z * p[j][k].z + xv.w * p[j][k].w;
      }
    }
    // transpose-butterfly: 3 splitting levels (8->1 values/lane), then 3 plain
#pragma unroll
    for (int lev = 0; lev < 3; ++lev) {
      const int d = 1 << lev;
      const int half = 4 >> lev;
#pragma unroll
      for (int i = 0; i < half; ++i) {
        float lo = v[i], hi = v[i + half];
        float keep = (lane & d) ? hi : lo;
        float oth  = (lane & d) ? lo : hi;
        v[i] = keep + __shfl_xor(oth, d, 64);
      }
    }
    float tot = v[0];
    tot += __shfl_xor(tot, 8, 64);
    tot += __shfl_xor(tot, 16, 64);
    tot += __shfl_xor(tot, 32, 64);

    const float w = __expf(tot);
    sumw_own += w;                       // lanes>=8 replicate; only lanes<8 stored
    if (lane < 8) w_tile[2 * rg + r_l][4 * hg + h_l] = w;

    __syncthreads();   // w_tile visible; x_tile[buf] still intact

    // ---- phase B: cols {2t,2t+1} x 8 heads over the 8 rows
    const float wv = ((const float*)w_tile)[lane];   // lane = r*8 + h
#pragma unroll
    for (int r = 0; r < TILE_R; ++r) {
      const float2 x2 = *(const float2*)&x_tile[buf][r][2 * t];
#pragma unroll
      for (int h = 0; h < NHEAD; ++h) {
        const float wr = __int_as_float(
            __builtin_amdgcn_readlane(__float_as_int(wv), r * NHEAD + h));
        acc[2 * h]     += wr * x2.x;
        acc[2 * h + 1] += wr * x2.y;
      }
    }
  }

  // write block partial z directly from registers (coalesced per head)
  {
    float* zd = partial_z + (size_t)blockIdx.x * (NHEAD * E_DIM) + 2 * t;
#pragma unroll
    for (int h = 0; h < NHEAD; ++h)
      *(float2*)(zd + h * E_DIM) = make_float2(acc[2 * h], acc[2 * h + 1]);
  }

  // sum-of-weights: combine row-parity lanes, stage per wave, reduce by 8 threads
  {
    float s2 = sumw_own + __shfl_xor(sumw_own, 1, 64);
    if (lane < 8 && (lane & 1) == 0) sw_stage[wave][h_l] = s2;
  }
  __syncthreads();
  if (t < NHEAD) {
    const int hgq = t >> 2, hlq = t & 3;
    float s = 0.f;
#pragma unroll
    for (int rgq = 0; rgq < 4; ++rgq) s += sw_stage[rgq * 2 + hgq][hlq];
    partial_sumw[blockIdx.x * NHEAD + t] = s;
  }
}

// ---------------- reduce partials: zn[h][e] = sum_b pz / sum_b psumw ----------------
__global__ __launch_bounds__(256) void reduce_z(
    const float* __restrict__ partial_z,
    const float* __restrict__ partial_sumw,
    float* __restrict__ zn, int nblk)
{
  __shared__ float red[256];
  __shared__ __align__(16) float swst[4][NHEAD];
  __shared__ float sumw_s[NHEAD];
  const int t = threadIdx.x;
  const int lane = t & 63, wave = t >> 6;

  float sw[NHEAD];
#pragma unroll
  for (int h = 0; h < NHEAD; ++h) sw[h] = 0.f;
  for (int b = t; b < nblk; b += 256) {
    const float4* p = (const float4*)(partial_sumw + (size_t)b * NHEAD);
    float4 a0 = p[0], a1 = p[1];
    sw[0] += a0.x; sw[1] += a0.y; sw[2] += a0.z; sw[3] += a0.w;
    sw[4] += a1.x; sw[5] += a1.y; sw[6] += a1.z; sw[7] += a1.w;
  }
#pragma unroll
  for (int m = 1; m < 64; m <<= 1) {
#pragma unroll
    for (int h = 0; h < NHEAD; ++h) sw[h] += __shfl_xor(sw[h], m, 64);
  }
  if (lane == 0) {
#pragma unroll
    for (int h = 0; h < NHEAD; ++h) swst[wave][h] = sw[h];
  }
  __syncthreads();
  if (t < NHEAD) sumw_s[t] = swst[0][t] + swst[1][t] + swst[2][t] + swst[3][t];

  const int o = blockIdx.x * 32 + (t & 31);
  const int g = t >> 5;
  float a = 0.f;
  for (int b = g; b < nblk; b += 8) a += partial_z[(size_t)b * (NHEAD * E_DIM) + o];
  red[t] = a;
  __syncthreads();
  if (t < 32) {
    float s2 = 0.f;
#pragma unroll
    for (int gg = 0; gg < 8; ++gg) s2 += red[gg * 32 + t];
    const int oo = blockIdx.x * 32 + t;
    zn[oo] = s2 / sumw_s[oo >> 10];   // oo = h*1024 + e
  }
}

// ---------------- attn[o] = Wv[o] . zn[h(o)] + bv[o] ----------------
__global__ __launch_bounds__(256) void proj_v(
    const float* __restrict__ W, const float* __restrict__ bias,
    const float* __restrict__ zn, float* __restrict__ attn)
{
  const int t = threadIdx.x, wave = t >> 6, lane = t & 63;
  const int o = blockIdx.x * 4 + wave;
  const float4* Wr = (const float4*)(W + ((size_t)2 * E_DIM + o) * E_DIM);
  const float4* zr = (const float4*)(zn + (size_t)(o >> 7) * E_DIM);
  float a = 0.f;
#pragma unroll
  for (int k = 0; k < 4; ++k) {
    float4 wv = Wr[lane + 64 * k];
    float4 zv = zr[lane + 64 * k];
    a += wv.x * zv.x + wv.y * zv.y + wv.z * zv.z + wv.w * zv.w;
  }
#pragma unroll
  for (int m = 1; m < 64; m <<= 1) a += __shfl_xor(a, m, 64);
  if (lane == 0) attn[o] = a + bias[2 * E_DIM + o];
}

// ---------------- out[e] = Wo[e] . attn + bo[e] ----------------
__global__ __launch_bounds__(256) void proj_o(
    const float* __restrict__ Wo, const float* __restrict__ bo,
    const float* __restrict__ attn, float* __restrict__ out)
{
  const int t = threadIdx.x, wave = t >> 6, lane = t & 63;
  const int o = blockIdx.x * 4 + wave;
  const float4* Wr = (const float4*)(Wo + (size_t)o * E_DIM);
  const float4* vr = (const float4*)attn;
  float a = 0.f;
#pragma unroll
  for (int k = 0; k < 4; ++k) {
    float4 wv = Wr[lane + 64 * k];
    float4 vv = vr[lane + 64 * k];
    a += wv.x * vv.x + wv.y * vv.y + wv.z * vv.z + wv.w * vv.w;
  }
#pragma unroll
  for (int m = 1; m < 64; m <<= 1) a += __shfl_xor(a, m, 64);
  if (lane == 0) out[o] = a + bo[o];
}

extern "C" void kernel_launch(void* const* d_in, const int* in_sizes, int n_in,
                              void* d_out, int out_size, void* d_ws, size_t ws_size,
                              hipStream_t stream)
{
  const float* x  = (const float*)d_in[0];   // [32768,1024]
  const float* Wi = (const float*)d_in[1];   // [3072,1024]
  const float* bi = (const float*)d_in[2];   // [3072]
  const float* Wo = (const float*)d_in[3];   // [1024,1024]
  const float* bo = (const float*)d_in[4];   // [1024]
  float* out = (float*)d_out;                // [1024] fp32

  // workspace layout (bytes)
  char* ws = (char*)d_ws;
  float* q     = (float*)(ws + 0);          // 1024 f
  float* P_T   = (float*)(ws + 4096);       // 8192 f
  float* zn    = (float*)(ws + 36864);      // 8192 f
  float* attn  = (float*)(ws + 69632);      // 1024 f
  float* psumw = (float*)(ws + 73728);      // nblk*8 f (<= 16 KB)
  const size_t pz_off = 90112;
  float* pz    = (float*)(ws + pz_off);     // nblk*8192 f

  // pick partial-block count from available workspace (constant across calls)
  int nblk = 128;
  if (ws_size >= pz_off + (size_t)512 * NHEAD * E_DIM * 4) nblk = 512;
  else if (ws_size >= pz_off + (size_t)256 * NHEAD * E_DIM * 4) nblk = 256;
  const int rows_per_blk = L_SEQ / nblk;

  proj_q     <<<256, 256, 0, stream>>>(Wi, bi, x, q);
  make_p     <<<dim3(8, 8), 128, 0, stream>>>(Wi, q, P_T);
  attn_fused5<<<nblk, 512, 0, stream>>>(x, P_T, pz, psumw, rows_per_blk);
  reduce_z   <<<256, 256, 0, stream>>>(pz, psumw, zn, nblk);
  proj_v     <<<256, 256, 0, stream>>>(Wi, bi, zn, attn);
  proj_o     <<<256, 256, 0, stream>>>(Wo, bo, attn, out);
}